// Round 8
// baseline (211.324 us; speedup 1.0000x reference)
//
#include <hip/hip_runtime.h>

#define S_LEN 2048
#define DMODEL 1024
#define NHEAD 16
#define DHEAD 64
#define BATCH 2
#define BH_TOT (BATCH * NHEAD)   // 32
#define TOK (BATCH * S_LEN)      // 4096
#define NQKV (3 * DMODEL)        // 3072

// softmax scale 1/sqrt(64) = 0.125, fused with log2(e): scores land in log2 domain
#define QSCALE 0.18033688011112042f

typedef float  f32x4  __attribute__((ext_vector_type(4)));
typedef __bf16 bf16x8 __attribute__((ext_vector_type(8)));
typedef __bf16 bf16x4 __attribute__((ext_vector_type(4)));
typedef __bf16 bf16x2 __attribute__((ext_vector_type(2)));
typedef short  s16x4  __attribute__((ext_vector_type(4)));

typedef __attribute__((address_space(1))) void* as1_ptr;
typedef __attribute__((address_space(3))) void* as3_ptr;

__device__ __forceinline__ void gl2lds16(const void* g, void* l) {
  __builtin_amdgcn_global_load_lds((as1_ptr)(void*)g, (as3_ptr)l, 16, 0, 0);
}

__device__ __forceinline__ f32x4 mfma32(bf16x8 a, bf16x8 b, f32x4 c) {
  return __builtin_amdgcn_mfma_f32_16x16x32_bf16(a, b, c, 0, 0, 0);
}
// 16x16x16 bf16: A[m=lane&15][k=quad*4+i], B[k=quad*4+i][n=lane&15] — B matches QK^T C-layout
__device__ __forceinline__ f32x4 mfma16(bf16x4 a, bf16x4 b, f32x4 c) {
  return __builtin_amdgcn_mfma_f32_16x16x16bf16_1k(
      __builtin_bit_cast(s16x4, a), __builtin_bit_cast(s16x4, b), c, 0, 0, 0);
}

// ---------------------------------------------------------------- fused convert f32 -> bf16 (x, Wqkv, Wout)
#define NX (TOK * DMODEL)          // 4194304
#define NW1 (NQKV * DMODEL)        // 3145728
#define NW2 (DMODEL * DMODEL)      // 1048576
__global__ __launch_bounds__(256) void cvt_all_kernel(const float* __restrict__ x,
                                                      const float* __restrict__ W1,
                                                      const float* __restrict__ W2,
                                                      __bf16* __restrict__ xb,
                                                      __bf16* __restrict__ W1b,
                                                      __bf16* __restrict__ W2b) {
  const int i = (blockIdx.x * 256 + threadIdx.x) * 4;
  const float* src;
  __bf16* dst;
  int off;
  if (i < NX)            { src = x;  dst = xb;  off = i; }
  else if (i < NX + NW1) { src = W1; dst = W1b; off = i - NX; }
  else                   { src = W2; dst = W2b; off = i - NX - NW1; }
  const f32x4 v = *(const f32x4*)(src + off);
  bf16x4 o;
  o[0] = (__bf16)v[0]; o[1] = (__bf16)v[1]; o[2] = (__bf16)v[2]; o[3] = (__bf16)v[3];
  *(bf16x4*)(dst + off) = o;
}

// ---------------------------------------------------------------- 128x128 bf16 GEMM mainloop
__device__ __forceinline__ void gemm_tile_128(const __bf16* __restrict__ A,
                                              const __bf16* __restrict__ Bw,
                                              const int Kd, const int tileM, const int tileN,
                                              __bf16* As, __bf16* Bs, f32x4 acc[4][4]) {
  const int t    = threadIdx.x;
  const int lane = t & 63;
  const int wave = t >> 6;
  const int quad = lane >> 4;
  const int c    = lane & 15;
  const int wm   = (wave >> 1) << 6;
  const int wn   = (wave & 1) << 6;

  const int u0 = t, u1 = t + 256;
  const __bf16* gA0 = A  + (size_t)(tileM + (u0 >> 2)) * Kd + (u0 & 3) * 8;
  const __bf16* gA1 = A  + (size_t)(tileM + (u1 >> 2)) * Kd + (u1 & 3) * 8;
  const __bf16* gB0 = Bw + (size_t)(tileN + (u0 >> 2)) * Kd + (u0 & 3) * 8;
  const __bf16* gB1 = Bw + (size_t)(tileN + (u1 >> 2)) * Kd + (u1 & 3) * 8;
  __bf16* lA0 = As + u0 * 8; __bf16* lA1 = As + u1 * 8;
  __bf16* lB0 = Bs + u0 * 8; __bf16* lB1 = Bs + u1 * 8;

  for (int k0 = 0; k0 < Kd; k0 += 32) {
    gl2lds16(gA0 + k0, lA0);
    gl2lds16(gA1 + k0, lA1);
    gl2lds16(gB0 + k0, lB0);
    gl2lds16(gB1 + k0, lB1);
    __syncthreads();
    bf16x8 af[4], bfr[4];
#pragma unroll
    for (int mt = 0; mt < 4; ++mt)
      af[mt] = *(const bf16x8*)(As + (wm + mt * 16 + c) * 32 + quad * 8);
#pragma unroll
    for (int nt = 0; nt < 4; ++nt)
      bfr[nt] = *(const bf16x8*)(Bs + (wn + nt * 16 + c) * 32 + quad * 8);
#pragma unroll
    for (int mt = 0; mt < 4; ++mt)
#pragma unroll
      for (int nt = 0; nt < 4; ++nt)
        acc[mt][nt] = mfma32(af[mt], bfr[nt], acc[mt][nt]);
    __syncthreads();
  }
}

// ---------------------------------------------------------------- QKV projection (+V transpose fused, +Q log2-scale)
__global__ __launch_bounds__(256) void gemm_qkv_kernel(const __bf16* __restrict__ xb,
                                                       const __bf16* __restrict__ Wb,
                                                       const float* __restrict__ bias,
                                                       __bf16* __restrict__ Qb,
                                                       __bf16* __restrict__ Kb,
                                                       __bf16* __restrict__ Vtb) {
  __shared__ __align__(16) __bf16 As[128 * 32];
  __shared__ __align__(16) __bf16 Bs[128 * 32];
  f32x4 acc[4][4];
#pragma unroll
  for (int i = 0; i < 4; ++i)
#pragma unroll
    for (int j = 0; j < 4; ++j) acc[i][j] = (f32x4){0.f, 0.f, 0.f, 0.f};

  const int tileM = blockIdx.y * 128;
  const int tileN = blockIdx.x * 128;
  gemm_tile_128(xb, Wb, DMODEL, tileM, tileN, As, Bs, acc);

  const int t = threadIdx.x;
  const int lane = t & 63, wave = t >> 6;
  const int quad = lane >> 4, c = lane & 15;
  const int wm = (wave >> 1) << 6, wn = (wave & 1) << 6;

#pragma unroll
  for (int nt = 0; nt < 4; ++nt) {
    const int col = tileN + wn + nt * 16 + c;
    const float bv = bias[col];
    const int which = col >> 10;         // 0=q,1=k,2=v  (uniform within 16-col group)
    const int h  = (col >> 6) & 15;
    const int dh = col & 63;
    if (which == 2) {
      // V: write directly transposed [bh][d][s], 4 consecutive tokens packed
#pragma unroll
      for (int mt = 0; mt < 4; ++mt) {
        const int row0 = tileM + wm + mt * 16 + quad * 4;
        const int bb = row0 >> 11;
        const int ss = row0 & (S_LEN - 1);
        bf16x4 o;
#pragma unroll
        for (int r = 0; r < 4; ++r) o[r] = (__bf16)(acc[mt][nt][r] + bv);
        *(bf16x4*)(Vtb + (((size_t)(bb * NHEAD + h)) * DHEAD + dh) * S_LEN + ss) = o;
      }
    } else {
      __bf16* dst = (which == 0) ? Qb : Kb;
      const float scl = (which == 0) ? QSCALE : 1.0f;
#pragma unroll
      for (int mt = 0; mt < 4; ++mt) {
#pragma unroll
        for (int r = 0; r < 4; ++r) {
          const int row = tileM + wm + mt * 16 + quad * 4 + r;
          const int bb = row >> 11;
          const int ss = row & (S_LEN - 1);
          dst[(((size_t)(bb * NHEAD + h)) * S_LEN + ss) * DHEAD + dh] =
              (__bf16)((acc[mt][nt][r] + bv) * scl);
        }
      }
    }
  }
}

// ---------------------------------------------------------------- output projection
__global__ __launch_bounds__(256) void gemm_out_kernel(const __bf16* __restrict__ AOb,
                                                       const __bf16* __restrict__ Wb,
                                                       const float* __restrict__ bout,
                                                       float* __restrict__ out) {
  __shared__ __align__(16) __bf16 As[128 * 32];
  __shared__ __align__(16) __bf16 Bs[128 * 32];
  f32x4 acc[4][4];
#pragma unroll
  for (int i = 0; i < 4; ++i)
#pragma unroll
    for (int j = 0; j < 4; ++j) acc[i][j] = (f32x4){0.f, 0.f, 0.f, 0.f};

  const int tileM = blockIdx.y * 128;
  const int tileN = blockIdx.x * 128;
  gemm_tile_128(AOb, Wb, DMODEL, tileM, tileN, As, Bs, acc);

  const int t = threadIdx.x;
  const int lane = t & 63, wave = t >> 6;
  const int quad = lane >> 4, c = lane & 15;
  const int wm = (wave >> 1) << 6, wn = (wave & 1) << 6;

#pragma unroll
  for (int nt = 0; nt < 4; ++nt) {
    const int col = tileN + wn + nt * 16 + c;
    const float bv = bout[col];
#pragma unroll
    for (int mt = 0; mt < 4; ++mt) {
#pragma unroll
      for (int r = 0; r < 4; ++r) {
        const int row = tileM + wm + mt * 16 + quad * 4 + r;
        out[(size_t)row * DMODEL + col] = acc[mt][nt][r] + bv;
      }
    }
  }
}

// ---------------------------------------------------------------- partial interleaved RoPE (proven standalone kernel)
__global__ __launch_bounds__(256) void rope_kernel(__bf16* __restrict__ Qb, __bf16* __restrict__ Kb) {
  const int idx = blockIdx.x * 256 + threadIdx.x;   // [0, 2*32*2048*16)
  const int j  = idx & 15;                          // rotation pair (dims 2j, 2j+1)
  const int s  = (idx >> 4) & (S_LEN - 1);
  const int bh = (idx >> 15) & (BH_TOT - 1);
  __bf16* base = (idx >> 20) ? Kb : Qb;
  bf16x2* p = (bf16x2*)(base + ((size_t)bh * S_LEN + s) * DHEAD) + j;
  bf16x2 v = *p;
  const float x1 = (float)v[0];
  const float x2 = (float)v[1];
  const float LOG2_10000 = 13.287712379549449f;
  const float inv = exp2f(-(float)j * (LOG2_10000 / 16.0f));
  const float ang = (float)s * inv;
  float sn, cs;
  sincosf(ang, &sn, &cs);
  bf16x2 o;
  o[0] = (__bf16)(x1 * cs - x2 * sn);
  o[1] = (__bf16)(x2 * cs + x1 * sn);
  *p = o;
}

// ---------------------------------------------------------------- flash attention R7
// Same structure as R4 (key-split across waves, P in registers, no-max exp2 softmax), but:
//  * staging via explicit global loads (LINEAR source, coalesced) + ds_write_b128 to the
//    XOR-swizzled dest slot s = g ^ (row&7). Invariant stored[r][s] = global[r][s^(r&7)]
//    is preserved, so ALL read paths are identical to R4. (global_load_lds suspected of not
//    honoring permuted per-lane source addresses.)
//  * no LDS aliasing: Ks | Vts | Os | Ls disjoint (51200 B dynamic, still 3 blocks/CU).
__global__ __launch_bounds__(256, 3) void attn_kernel(const __bf16* __restrict__ Qb,
                                                      const __bf16* __restrict__ Kb,
                                                      const __bf16* __restrict__ Vtb,
                                                      __bf16* __restrict__ AOb) {
  extern __shared__ __align__(16) char smem[];
  __bf16* KsB  = (__bf16*)smem;                    // [0,16384): 2 buffers x 4096 elem
  __bf16* VtsB = (__bf16*)(smem + 16384);          // [16384,32768)
  float*  Os   = (float*)(smem + 32768);           // [32768,50176): 64*68 fp32
  float*  Ls   = (float*)(smem + 50176);           // [50176,51200): 256 fp32

  const int qt = blockIdx.x;
  const int bh = blockIdx.y;
  const int b = bh >> 4, h = bh & 15;
  const int t = threadIdx.x, wave = t >> 6, lane = t & 63;
  const int quad = lane >> 4, c = lane & 15;
  const size_t head = (size_t)bh * S_LEN * DHEAD;
  const int q0 = qt * 64;

  // Q B-fragments (all 64 q resident): qf[nq][hh]: B[k=d=hh*32+quad*8+j][n=q=nq*16+c]
  bf16x8 qf[4][2];
#pragma unroll
  for (int nq = 0; nq < 4; ++nq) {
    const __bf16* qp = Qb + head + (size_t)(q0 + nq * 16 + c) * DHEAD + quad * 8;
    qf[nq][0] = *(const bf16x8*)qp;
    qf[nq][1] = *(const bf16x8*)(qp + 32);
  }

  f32x4 ot[4][4];   // O^T partial (this wave's keys): [dt][nq]; lane: d=dt*16+quad*4+r, q=nq*16+c
#pragma unroll
  for (int dt = 0; dt < 4; ++dt)
#pragma unroll
    for (int nq = 0; nq < 4; ++nq) ot[dt][nq] = (f32x4){0.f, 0.f, 0.f, 0.f};
  float lp[4] = {0.f, 0.f, 0.f, 0.f};

  // staging: unit u -> row r=u>>3, LINEAR source chunk g=u&7, dest slot s=g^(r&7)
  const int u0 = t, u1 = t + 256;
  const int r0 = u0 >> 3, g0 = u0 & 7, sl0 = g0 ^ (r0 & 7);
  const int r1 = u1 >> 3, g1 = u1 & 7, sl1 = g1 ^ (r1 & 7);
  const __bf16* kg0 = Kb + head + (size_t)r0 * DHEAD + g0 * 8;
  const __bf16* kg1 = Kb + head + (size_t)r1 * DHEAD + g1 * 8;
  const __bf16* vg0 = Vtb + ((size_t)bh * DHEAD + r0) * S_LEN + g0 * 8;
  const __bf16* vg1 = Vtb + ((size_t)bh * DHEAD + r1) * S_LEN + g1 * 8;
  const int kd0 = r0 * 64 + sl0 * 8;   // dest offset (elements) within a buffer
  const int kd1 = r1 * 64 + sl1 * 8;

  // preload tile 0 -> buffer 0
  {
    const bf16x8 a0 = *(const bf16x8*)kg0;
    const bf16x8 a1 = *(const bf16x8*)kg1;
    const bf16x8 b0 = *(const bf16x8*)vg0;
    const bf16x8 b1 = *(const bf16x8*)vg1;
    *(bf16x8*)(KsB + kd0) = a0;
    *(bf16x8*)(KsB + kd1) = a1;
    *(bf16x8*)(VtsB + kd0) = b0;
    *(bf16x8*)(VtsB + kd1) = b1;
  }

  const int cxor = c & 7;
  const int kArow = (wave * 16 + c) * 64;            // this wave's K rows
  const int vchunk = wave * 2 + (quad >> 1);         // 16B chunk of this wave's keys
  const int vsub = (quad & 1) * 4;

  for (int kb = 0; kb < S_LEN / 64; ++kb) {
    __syncthreads();   // all prior ds_writes + reads drained; tile cur complete
    const int cur = (kb & 1) * 4096;                 // buffer offset in __bf16 units
    const bool pre = (kb + 1 < S_LEN / 64);
    bf16x8 pk0, pk1, pv0, pv1;
    if (pre) {
      const int k0n = (kb + 1) * 64;
      pk0 = *(const bf16x8*)(kg0 + (size_t)k0n * DHEAD);
      pk1 = *(const bf16x8*)(kg1 + (size_t)k0n * DHEAD);
      pv0 = *(const bf16x8*)(vg0 + k0n);
      pv1 = *(const bf16x8*)(vg1 + k0n);
    }

    // K A-fragments for this wave's 16 keys: A[m=key=c][k=d]
    const bf16x8 kA0 = *(const bf16x8*)(KsB + cur + kArow + ((0 + quad) ^ cxor) * 8);
    const bf16x8 kA1 = *(const bf16x8*)(KsB + cur + kArow + ((4 + quad) ^ cxor) * 8);

    // V^T A-fragments: A[m=d=dt*16+c][k=wave-local key quad*4+i]
    bf16x4 vA[4];
#pragma unroll
    for (int dt = 0; dt < 4; ++dt)
      vA[dt] = *(const bf16x4*)(VtsB + cur + (dt * 16 + c) * 64 + ((vchunk ^ cxor) * 8) + vsub);

    // scores (lane: q=nq*16+c, key=quad*4+r) -> exp2 -> P fragments (B-layout for mfma16)
#pragma unroll
    for (int nq = 0; nq < 4; ++nq) {
      f32x4 z = (f32x4){0.f, 0.f, 0.f, 0.f};
      z = mfma32(kA0, qf[nq][0], z);
      z = mfma32(kA1, qf[nq][1], z);
      bf16x4 pf;
#pragma unroll
      for (int r = 0; r < 4; ++r) {
        const float p = __builtin_amdgcn_exp2f(z[r]);
        lp[nq] += p;
        pf[r] = (__bf16)p;
      }
#pragma unroll
      for (int dt = 0; dt < 4; ++dt)
        ot[dt][nq] = mfma16(vA[dt], pf, ot[dt][nq]);
    }

    if (pre) {
      const int nxt = ((kb + 1) & 1) * 4096;
      *(bf16x8*)(KsB + nxt + kd0) = pk0;
      *(bf16x8*)(KsB + nxt + kd1) = pk1;
      *(bf16x8*)(VtsB + nxt + kd0) = pv0;
      *(bf16x8*)(VtsB + nxt + kd1) = pv1;
    }
  }

  // l partials: reduce over quads (same q lives in 4 lanes), publish per wave
#pragma unroll
  for (int nq = 0; nq < 4; ++nq) {
    float v = lp[nq];
    v += __shfl_xor(v, 16);
    v += __shfl_xor(v, 32);
    if (lane < 16) Ls[(wave * 4 + nq) * 16 + lane] = v;
  }

  // O: sequential cross-wave accumulate into Os[q][d] (disjoint LDS region)
  for (int w = 0; w < 4; ++w) {
    __syncthreads();
    if (wave == w) {
#pragma unroll
      for (int nq = 0; nq < 4; ++nq) {
#pragma unroll
        for (int dt = 0; dt < 4; ++dt) {
          float* p = Os + (nq * 16 + c) * 68 + dt * 16 + quad * 4;
          if (w == 0) *(f32x4*)p = ot[dt][nq];
          else        *(f32x4*)p = *(const f32x4*)p + ot[dt][nq];
        }
      }
    }
  }
  __syncthreads();

  // epilogue: thread t -> q = t>>2, 16-d chunk = (t&3)*16
  const int q = t >> 2, dc = t & 3;
  const int nq = q >> 4, cc = q & 15;
  const float lsum = Ls[(0 * 4 + nq) * 16 + cc] + Ls[(1 * 4 + nq) * 16 + cc] +
                     Ls[(2 * 4 + nq) * 16 + cc] + Ls[(3 * 4 + nq) * 16 + cc];
  const float inv = 1.0f / lsum;
  const float* orow = Os + q * 68 + dc * 16;
  f32x4 v0 = *(const f32x4*)(orow + 0);
  f32x4 v1 = *(const f32x4*)(orow + 4);
  f32x4 v2 = *(const f32x4*)(orow + 8);
  f32x4 v3 = *(const f32x4*)(orow + 12);
  bf16x8 o0, o1;
#pragma unroll
  for (int i = 0; i < 4; ++i) {
    o0[i]     = (__bf16)(v0[i] * inv);
    o0[i + 4] = (__bf16)(v1[i] * inv);
    o1[i]     = (__bf16)(v2[i] * inv);
    o1[i + 4] = (__bf16)(v3[i] * inv);
  }
  __bf16* dst = AOb + ((size_t)(b * S_LEN + q0 + q)) * DMODEL + h * DHEAD + dc * 16;
  *(bf16x8*)dst = o0;
  *(bf16x8*)(dst + 8) = o1;
}

// ---------------------------------------------------------------- launch
extern "C" void kernel_launch(void* const* d_in, const int* in_sizes, int n_in,
                              void* d_out, int out_size, void* d_ws, size_t ws_size,
                              hipStream_t stream) {
  const float* x    = (const float*)d_in[0];
  const float* Wqkv = (const float*)d_in[1];
  const float* bqkv = (const float*)d_in[2];
  const float* Wout = (const float*)d_in[3];
  const float* bout = (const float*)d_in[4];
  float* out = (float*)d_out;

  char* ws = (char*)d_ws;
  __bf16* xb    = (__bf16*)(ws + 0);                          //  8 MB (4096x1024)
  __bf16* Wqkvb = (__bf16*)(ws + (size_t)8  * 1024 * 1024);   //  6 MB (3072x1024)
  __bf16* Woutb = (__bf16*)(ws + (size_t)14 * 1024 * 1024);   //  2 MB (1024x1024)
  __bf16* Qb    = (__bf16*)(ws + (size_t)16 * 1024 * 1024);   //  8 MB [bh][s][d] (pre-scaled)
  __bf16* Kb    = (__bf16*)(ws + (size_t)24 * 1024 * 1024);   //  8 MB [bh][s][d]
  __bf16* Vtb   = (__bf16*)(ws + (size_t)32 * 1024 * 1024);   //  8 MB [bh][d][s]
  __bf16* AOb   = (__bf16*)(ws + (size_t)40 * 1024 * 1024);   //  8 MB [b][s][dm]

  cvt_all_kernel<<<(NX + NW1 + NW2) / 1024, 256, 0, stream>>>(x, Wqkv, Wout, xb, Wqkvb, Woutb);

  gemm_qkv_kernel<<<dim3(NQKV / 128, TOK / 128), 256, 0, stream>>>(xb, Wqkvb, bqkv, Qb, Kb, Vtb);

  rope_kernel<<<(2 * BH_TOT * S_LEN * 16) / 256, 256, 0, stream>>>(Qb, Kb);

  attn_kernel<<<dim3(S_LEN / 64, BH_TOT), 256, 51200, stream>>>(Qb, Kb, Vtb, AOb);

  gemm_out_kernel<<<dim3(DMODEL / 128, TOK / 128), 256, 0, stream>>>(AOb, Woutb, bout, out);
}

// Round 9
// 205.576 us; speedup vs baseline: 1.0280x; 1.0280x over previous
//
#include <hip/hip_runtime.h>

#define S_LEN 2048
#define DMODEL 1024
#define NHEAD 16
#define DHEAD 64
#define BATCH 2
#define BH_TOT (BATCH * NHEAD)   // 32
#define TOK (BATCH * S_LEN)      // 4096
#define NQKV (3 * DMODEL)        // 3072

// softmax scale 1/sqrt(64) = 0.125, fused with log2(e): scores land in log2 domain
#define QSCALE 0.18033688011112042f

typedef float  f32x4  __attribute__((ext_vector_type(4)));
typedef __bf16 bf16x8 __attribute__((ext_vector_type(8)));
typedef __bf16 bf16x4 __attribute__((ext_vector_type(4)));
typedef __bf16 bf16x2 __attribute__((ext_vector_type(2)));
typedef short  s16x4  __attribute__((ext_vector_type(4)));

typedef __attribute__((address_space(1))) void* as1_ptr;
typedef __attribute__((address_space(3))) void* as3_ptr;

__device__ __forceinline__ void gl2lds16(const void* g, void* l) {
  __builtin_amdgcn_global_load_lds((as1_ptr)(void*)g, (as3_ptr)l, 16, 0, 0);
}

__device__ __forceinline__ f32x4 mfma32(bf16x8 a, bf16x8 b, f32x4 c) {
  return __builtin_amdgcn_mfma_f32_16x16x32_bf16(a, b, c, 0, 0, 0);
}
// 16x16x16 bf16: A[m=lane&15][k=quad*4+i], B[k=quad*4+i][n=lane&15] — B matches QK^T C-layout
__device__ __forceinline__ f32x4 mfma16(bf16x4 a, bf16x4 b, f32x4 c) {
  return __builtin_amdgcn_mfma_f32_16x16x16bf16_1k(
      __builtin_bit_cast(s16x4, a), __builtin_bit_cast(s16x4, b), c, 0, 0, 0);
}

// ---------------------------------------------------------------- fused convert f32 -> bf16 (x, Wqkv, Wout)
#define NX (TOK * DMODEL)          // 4194304
#define NW1 (NQKV * DMODEL)        // 3145728
#define NW2 (DMODEL * DMODEL)      // 1048576
__global__ __launch_bounds__(256) void cvt_all_kernel(const float* __restrict__ x,
                                                      const float* __restrict__ W1,
                                                      const float* __restrict__ W2,
                                                      __bf16* __restrict__ xb,
                                                      __bf16* __restrict__ W1b,
                                                      __bf16* __restrict__ W2b) {
  const int i = (blockIdx.x * 256 + threadIdx.x) * 4;
  const float* src;
  __bf16* dst;
  int off;
  if (i < NX)            { src = x;  dst = xb;  off = i; }
  else if (i < NX + NW1) { src = W1; dst = W1b; off = i - NX; }
  else                   { src = W2; dst = W2b; off = i - NX - NW1; }
  const f32x4 v = *(const f32x4*)(src + off);
  bf16x4 o;
  o[0] = (__bf16)v[0]; o[1] = (__bf16)v[1]; o[2] = (__bf16)v[2]; o[3] = (__bf16)v[3];
  *(bf16x4*)(dst + off) = o;
}

// ---------------------------------------------------------------- 128x128 bf16 GEMM mainloop
__device__ __forceinline__ void gemm_tile_128(const __bf16* __restrict__ A,
                                              const __bf16* __restrict__ Bw,
                                              const int Kd, const int tileM, const int tileN,
                                              __bf16* As, __bf16* Bs, f32x4 acc[4][4]) {
  const int t    = threadIdx.x;
  const int lane = t & 63;
  const int wave = t >> 6;
  const int quad = lane >> 4;
  const int c    = lane & 15;
  const int wm   = (wave >> 1) << 6;
  const int wn   = (wave & 1) << 6;

  const int u0 = t, u1 = t + 256;
  const __bf16* gA0 = A  + (size_t)(tileM + (u0 >> 2)) * Kd + (u0 & 3) * 8;
  const __bf16* gA1 = A  + (size_t)(tileM + (u1 >> 2)) * Kd + (u1 & 3) * 8;
  const __bf16* gB0 = Bw + (size_t)(tileN + (u0 >> 2)) * Kd + (u0 & 3) * 8;
  const __bf16* gB1 = Bw + (size_t)(tileN + (u1 >> 2)) * Kd + (u1 & 3) * 8;
  __bf16* lA0 = As + u0 * 8; __bf16* lA1 = As + u1 * 8;
  __bf16* lB0 = Bs + u0 * 8; __bf16* lB1 = Bs + u1 * 8;

  for (int k0 = 0; k0 < Kd; k0 += 32) {
    gl2lds16(gA0 + k0, lA0);
    gl2lds16(gA1 + k0, lA1);
    gl2lds16(gB0 + k0, lB0);
    gl2lds16(gB1 + k0, lB1);
    __syncthreads();
    bf16x8 af[4], bfr[4];
#pragma unroll
    for (int mt = 0; mt < 4; ++mt)
      af[mt] = *(const bf16x8*)(As + (wm + mt * 16 + c) * 32 + quad * 8);
#pragma unroll
    for (int nt = 0; nt < 4; ++nt)
      bfr[nt] = *(const bf16x8*)(Bs + (wn + nt * 16 + c) * 32 + quad * 8);
#pragma unroll
    for (int mt = 0; mt < 4; ++mt)
#pragma unroll
      for (int nt = 0; nt < 4; ++nt)
        acc[mt][nt] = mfma32(af[mt], bfr[nt], acc[mt][nt]);
    __syncthreads();
  }
}

// ---------------------------------------------------------------- QKV projection (+V transpose fused, +Q log2-scale)
__global__ __launch_bounds__(256) void gemm_qkv_kernel(const __bf16* __restrict__ xb,
                                                       const __bf16* __restrict__ Wb,
                                                       const float* __restrict__ bias,
                                                       __bf16* __restrict__ Qb,
                                                       __bf16* __restrict__ Kb,
                                                       __bf16* __restrict__ Vtb) {
  __shared__ __align__(16) __bf16 As[128 * 32];
  __shared__ __align__(16) __bf16 Bs[128 * 32];
  f32x4 acc[4][4];
#pragma unroll
  for (int i = 0; i < 4; ++i)
#pragma unroll
    for (int j = 0; j < 4; ++j) acc[i][j] = (f32x4){0.f, 0.f, 0.f, 0.f};

  const int tileM = blockIdx.y * 128;
  const int tileN = blockIdx.x * 128;
  gemm_tile_128(xb, Wb, DMODEL, tileM, tileN, As, Bs, acc);

  const int t = threadIdx.x;
  const int lane = t & 63, wave = t >> 6;
  const int quad = lane >> 4, c = lane & 15;
  const int wm = (wave >> 1) << 6, wn = (wave & 1) << 6;

#pragma unroll
  for (int nt = 0; nt < 4; ++nt) {
    const int col = tileN + wn + nt * 16 + c;
    const float bv = bias[col];
    const int which = col >> 10;         // 0=q,1=k,2=v  (uniform within 16-col group)
    const int h  = (col >> 6) & 15;
    const int dh = col & 63;
    if (which == 2) {
      // V: write directly transposed [bh][d][s], 4 consecutive tokens packed
#pragma unroll
      for (int mt = 0; mt < 4; ++mt) {
        const int row0 = tileM + wm + mt * 16 + quad * 4;
        const int bb = row0 >> 11;
        const int ss = row0 & (S_LEN - 1);
        bf16x4 o;
#pragma unroll
        for (int r = 0; r < 4; ++r) o[r] = (__bf16)(acc[mt][nt][r] + bv);
        *(bf16x4*)(Vtb + (((size_t)(bb * NHEAD + h)) * DHEAD + dh) * S_LEN + ss) = o;
      }
    } else {
      __bf16* dst = (which == 0) ? Qb : Kb;
      const float scl = (which == 0) ? QSCALE : 1.0f;
#pragma unroll
      for (int mt = 0; mt < 4; ++mt) {
#pragma unroll
        for (int r = 0; r < 4; ++r) {
          const int row = tileM + wm + mt * 16 + quad * 4 + r;
          const int bb = row >> 11;
          const int ss = row & (S_LEN - 1);
          dst[(((size_t)(bb * NHEAD + h)) * S_LEN + ss) * DHEAD + dh] =
              (__bf16)((acc[mt][nt][r] + bv) * scl);
        }
      }
    }
  }
}

// ---------------------------------------------------------------- output projection
__global__ __launch_bounds__(256) void gemm_out_kernel(const __bf16* __restrict__ AOb,
                                                       const __bf16* __restrict__ Wb,
                                                       const float* __restrict__ bout,
                                                       float* __restrict__ out) {
  __shared__ __align__(16) __bf16 As[128 * 32];
  __shared__ __align__(16) __bf16 Bs[128 * 32];
  f32x4 acc[4][4];
#pragma unroll
  for (int i = 0; i < 4; ++i)
#pragma unroll
    for (int j = 0; j < 4; ++j) acc[i][j] = (f32x4){0.f, 0.f, 0.f, 0.f};

  const int tileM = blockIdx.y * 128;
  const int tileN = blockIdx.x * 128;
  gemm_tile_128(AOb, Wb, DMODEL, tileM, tileN, As, Bs, acc);

  const int t = threadIdx.x;
  const int lane = t & 63, wave = t >> 6;
  const int quad = lane >> 4, c = lane & 15;
  const int wm = (wave >> 1) << 6, wn = (wave & 1) << 6;

#pragma unroll
  for (int nt = 0; nt < 4; ++nt) {
    const int col = tileN + wn + nt * 16 + c;
    const float bv = bout[col];
#pragma unroll
    for (int mt = 0; mt < 4; ++mt) {
#pragma unroll
      for (int r = 0; r < 4; ++r) {
        const int row = tileM + wm + mt * 16 + quad * 4 + r;
        out[(size_t)row * DMODEL + col] = acc[mt][nt][r] + bv;
      }
    }
  }
}

// ---------------------------------------------------------------- partial interleaved RoPE (proven standalone kernel)
__global__ __launch_bounds__(256) void rope_kernel(__bf16* __restrict__ Qb, __bf16* __restrict__ Kb) {
  const int idx = blockIdx.x * 256 + threadIdx.x;   // [0, 2*32*2048*16)
  const int j  = idx & 15;                          // rotation pair (dims 2j, 2j+1)
  const int s  = (idx >> 4) & (S_LEN - 1);
  const int bh = (idx >> 15) & (BH_TOT - 1);
  __bf16* base = (idx >> 20) ? Kb : Qb;
  bf16x2* p = (bf16x2*)(base + ((size_t)bh * S_LEN + s) * DHEAD) + j;
  bf16x2 v = *p;
  const float x1 = (float)v[0];
  const float x2 = (float)v[1];
  const float LOG2_10000 = 13.287712379549449f;
  const float inv = exp2f(-(float)j * (LOG2_10000 / 16.0f));
  const float ang = (float)s * inv;
  float sn, cs;
  sincosf(ang, &sn, &cs);
  bf16x2 o;
  o[0] = (__bf16)(x1 * cs - x2 * sn);
  o[1] = (__bf16)(x2 * cs + x1 * sn);
  *p = o;
}

// ---------------------------------------------------------------- flash attention R8
// R7 structure (key-split across waves, P in registers, no-max exp2 softmax, explicit
// load + swizzled ds_write staging) with a DEPTH-2 REGISTER PIPELINE:
//   iteration kb: barrier -> ds_write regs(tile kb+1) -> buf[(kb+1)&1]
//                 -> issue global loads tile kb+2 -> fresh regs
//                 -> compute tile kb from buf[kb&1] -> roll regs.
// The global load's consumer (ds_write) is a full iteration away; the ds_write's consumer
// (barrier) is a full iteration away -> load latency off the critical path.
__global__ __launch_bounds__(256, 3) void attn_kernel(const __bf16* __restrict__ Qb,
                                                      const __bf16* __restrict__ Kb,
                                                      const __bf16* __restrict__ Vtb,
                                                      __bf16* __restrict__ AOb) {
  extern __shared__ __align__(16) char smem[];
  __bf16* KsB  = (__bf16*)smem;                    // [0,16384): 2 buffers x 4096 elem
  __bf16* VtsB = (__bf16*)(smem + 16384);          // [16384,32768)
  float*  Os   = (float*)(smem + 32768);           // [32768,50176): 64*68 fp32
  float*  Ls   = (float*)(smem + 50176);           // [50176,51200): 256 fp32

  const int qt = blockIdx.x;
  const int bh = blockIdx.y;
  const int b = bh >> 4, h = bh & 15;
  const int t = threadIdx.x, wave = t >> 6, lane = t & 63;
  const int quad = lane >> 4, c = lane & 15;
  const size_t head = (size_t)bh * S_LEN * DHEAD;
  const int q0 = qt * 64;

  // Q B-fragments (all 64 q resident): qf[nq][hh]: B[k=d=hh*32+quad*8+j][n=q=nq*16+c]
  bf16x8 qf[4][2];
#pragma unroll
  for (int nq = 0; nq < 4; ++nq) {
    const __bf16* qp = Qb + head + (size_t)(q0 + nq * 16 + c) * DHEAD + quad * 8;
    qf[nq][0] = *(const bf16x8*)qp;
    qf[nq][1] = *(const bf16x8*)(qp + 32);
  }

  f32x4 ot[4][4];   // O^T partial (this wave's keys): [dt][nq]; lane: d=dt*16+quad*4+r, q=nq*16+c
#pragma unroll
  for (int dt = 0; dt < 4; ++dt)
#pragma unroll
    for (int nq = 0; nq < 4; ++nq) ot[dt][nq] = (f32x4){0.f, 0.f, 0.f, 0.f};
  float lp[4] = {0.f, 0.f, 0.f, 0.f};

  // staging: unit u -> row r=u>>3, LINEAR source chunk g=u&7, dest slot s=g^(r&7)
  const int u0 = t, u1 = t + 256;
  const int r0 = u0 >> 3, g0 = u0 & 7, sl0 = g0 ^ (r0 & 7);
  const int r1 = u1 >> 3, g1 = u1 & 7, sl1 = g1 ^ (r1 & 7);
  const __bf16* kg0 = Kb + head + (size_t)r0 * DHEAD + g0 * 8;
  const __bf16* kg1 = Kb + head + (size_t)r1 * DHEAD + g1 * 8;
  const __bf16* vg0 = Vtb + ((size_t)bh * DHEAD + r0) * S_LEN + g0 * 8;
  const __bf16* vg1 = Vtb + ((size_t)bh * DHEAD + r1) * S_LEN + g1 * 8;
  const int kd0 = r0 * 64 + sl0 * 8;   // dest offset (elements) within a buffer
  const int kd1 = r1 * 64 + sl1 * 8;

  // preload: tile 0 -> buf0 directly; tile 1 -> regs (pipeline stage)
  bf16x8 pk0, pk1, pv0, pv1;
  {
    const bf16x8 a0 = *(const bf16x8*)kg0;
    const bf16x8 a1 = *(const bf16x8*)kg1;
    const bf16x8 b0 = *(const bf16x8*)vg0;
    const bf16x8 b1 = *(const bf16x8*)vg1;
    *(bf16x8*)(KsB + kd0) = a0;
    *(bf16x8*)(KsB + kd1) = a1;
    *(bf16x8*)(VtsB + kd0) = b0;
    *(bf16x8*)(VtsB + kd1) = b1;
    pk0 = *(const bf16x8*)(kg0 + (size_t)64 * DHEAD);
    pk1 = *(const bf16x8*)(kg1 + (size_t)64 * DHEAD);
    pv0 = *(const bf16x8*)(vg0 + 64);
    pv1 = *(const bf16x8*)(vg1 + 64);
  }

  const int cxor = c & 7;
  const int kArow = (wave * 16 + c) * 64;            // this wave's K rows
  const int vchunk = wave * 2 + (quad >> 1);         // 16B chunk of this wave's keys
  const int vsub = (quad & 1) * 4;

  for (int kb = 0; kb < S_LEN / 64; ++kb) {
    __syncthreads();   // buf[kb&1] complete; all waves done reading buf[(kb+1)&1]
    const int cur = (kb & 1) * 4096;                 // buffer offset in __bf16 units
    // stage tile kb+1 regs -> other buffer (consumer barrier is one iteration away)
    if (kb + 1 < S_LEN / 64) {
      const int nxt = ((kb + 1) & 1) * 4096;
      *(bf16x8*)(KsB + nxt + kd0) = pk0;
      *(bf16x8*)(KsB + nxt + kd1) = pk1;
      *(bf16x8*)(VtsB + nxt + kd0) = pv0;
      *(bf16x8*)(VtsB + nxt + kd1) = pv1;
    }
    // issue loads for tile kb+2 (consumer ds_write is one iteration away)
    bf16x8 nk0, nk1, nv0, nv1;
    const bool pre2 = (kb + 2 < S_LEN / 64);
    if (pre2) {
      const int k0n = (kb + 2) * 64;
      nk0 = *(const bf16x8*)(kg0 + (size_t)k0n * DHEAD);
      nk1 = *(const bf16x8*)(kg1 + (size_t)k0n * DHEAD);
      nv0 = *(const bf16x8*)(vg0 + k0n);
      nv1 = *(const bf16x8*)(vg1 + k0n);
    }

    // K A-fragments for this wave's 16 keys: A[m=key=c][k=d]
    const bf16x8 kA0 = *(const bf16x8*)(KsB + cur + kArow + ((0 + quad) ^ cxor) * 8);
    const bf16x8 kA1 = *(const bf16x8*)(KsB + cur + kArow + ((4 + quad) ^ cxor) * 8);

    // V^T A-fragments: A[m=d=dt*16+c][k=wave-local key quad*4+i]
    bf16x4 vA[4];
#pragma unroll
    for (int dt = 0; dt < 4; ++dt)
      vA[dt] = *(const bf16x4*)(VtsB + cur + (dt * 16 + c) * 64 + ((vchunk ^ cxor) * 8) + vsub);

    // scores (lane: q=nq*16+c, key=quad*4+r) -> exp2 -> P fragments (B-layout for mfma16)
#pragma unroll
    for (int nq = 0; nq < 4; ++nq) {
      f32x4 z = (f32x4){0.f, 0.f, 0.f, 0.f};
      z = mfma32(kA0, qf[nq][0], z);
      z = mfma32(kA1, qf[nq][1], z);
      bf16x4 pf;
#pragma unroll
      for (int r = 0; r < 4; ++r) {
        const float p = __builtin_amdgcn_exp2f(z[r]);
        lp[nq] += p;
        pf[r] = (__bf16)p;
      }
#pragma unroll
      for (int dt = 0; dt < 4; ++dt)
        ot[dt][nq] = mfma16(vA[dt], pf, ot[dt][nq]);
    }

    if (pre2) { pk0 = nk0; pk1 = nk1; pv0 = nv0; pv1 = nv1; }
  }

  // l partials: reduce over quads (same q lives in 4 lanes), publish per wave
#pragma unroll
  for (int nq = 0; nq < 4; ++nq) {
    float v = lp[nq];
    v += __shfl_xor(v, 16);
    v += __shfl_xor(v, 32);
    if (lane < 16) Ls[(wave * 4 + nq) * 16 + lane] = v;
  }

  // O: sequential cross-wave accumulate into Os[q][d] (disjoint LDS region)
  for (int w = 0; w < 4; ++w) {
    __syncthreads();
    if (wave == w) {
#pragma unroll
      for (int nq = 0; nq < 4; ++nq) {
#pragma unroll
        for (int dt = 0; dt < 4; ++dt) {
          float* p = Os + (nq * 16 + c) * 68 + dt * 16 + quad * 4;
          if (w == 0) *(f32x4*)p = ot[dt][nq];
          else        *(f32x4*)p = *(const f32x4*)p + ot[dt][nq];
        }
      }
    }
  }
  __syncthreads();

  // epilogue: thread t -> q = t>>2, 16-d chunk = (t&3)*16
  const int q = t >> 2, dc = t & 3;
  const int nq = q >> 4, cc = q & 15;
  const float lsum = Ls[(0 * 4 + nq) * 16 + cc] + Ls[(1 * 4 + nq) * 16 + cc] +
                     Ls[(2 * 4 + nq) * 16 + cc] + Ls[(3 * 4 + nq) * 16 + cc];
  const float inv = 1.0f / lsum;
  const float* orow = Os + q * 68 + dc * 16;
  f32x4 v0 = *(const f32x4*)(orow + 0);
  f32x4 v1 = *(const f32x4*)(orow + 4);
  f32x4 v2 = *(const f32x4*)(orow + 8);
  f32x4 v3 = *(const f32x4*)(orow + 12);
  bf16x8 o0, o1;
#pragma unroll
  for (int i = 0; i < 4; ++i) {
    o0[i]     = (__bf16)(v0[i] * inv);
    o0[i + 4] = (__bf16)(v1[i] * inv);
    o1[i]     = (__bf16)(v2[i] * inv);
    o1[i + 4] = (__bf16)(v3[i] * inv);
  }
  __bf16* dst = AOb + ((size_t)(b * S_LEN + q0 + q)) * DMODEL + h * DHEAD + dc * 16;
  *(bf16x8*)dst = o0;
  *(bf16x8*)(dst + 8) = o1;
}

// ---------------------------------------------------------------- launch
extern "C" void kernel_launch(void* const* d_in, const int* in_sizes, int n_in,
                              void* d_out, int out_size, void* d_ws, size_t ws_size,
                              hipStream_t stream) {
  const float* x    = (const float*)d_in[0];
  const float* Wqkv = (const float*)d_in[1];
  const float* bqkv = (const float*)d_in[2];
  const float* Wout = (const float*)d_in[3];
  const float* bout = (const float*)d_in[4];
  float* out = (float*)d_out;

  char* ws = (char*)d_ws;
  __bf16* xb    = (__bf16*)(ws + 0);                          //  8 MB (4096x1024)
  __bf16* Wqkvb = (__bf16*)(ws + (size_t)8  * 1024 * 1024);   //  6 MB (3072x1024)
  __bf16* Woutb = (__bf16*)(ws + (size_t)14 * 1024 * 1024);   //  2 MB (1024x1024)
  __bf16* Qb    = (__bf16*)(ws + (size_t)16 * 1024 * 1024);   //  8 MB [bh][s][d] (pre-scaled)
  __bf16* Kb    = (__bf16*)(ws + (size_t)24 * 1024 * 1024);   //  8 MB [bh][s][d]
  __bf16* Vtb   = (__bf16*)(ws + (size_t)32 * 1024 * 1024);   //  8 MB [bh][d][s]
  __bf16* AOb   = (__bf16*)(ws + (size_t)40 * 1024 * 1024);   //  8 MB [b][s][dm]

  cvt_all_kernel<<<(NX + NW1 + NW2) / 1024, 256, 0, stream>>>(x, Wqkv, Wout, xb, Wqkvb, Woutb);

  gemm_qkv_kernel<<<dim3(NQKV / 128, TOK / 128), 256, 0, stream>>>(xb, Wqkvb, bqkv, Qb, Kb, Vtb);

  rope_kernel<<<(2 * BH_TOT * S_LEN * 16) / 256, 256, 0, stream>>>(Qb, Kb);

  attn_kernel<<<dim3(S_LEN / 64, BH_TOT), 256, 51200, stream>>>(Qb, Kb, Vtb, AOb);

  gemm_out_kernel<<<dim3(DMODEL / 128, TOK / 128), 256, 0, stream>>>(AOb, Woutb, bout, out);
}